// Round 11
// baseline (415.733 us; speedup 1.0000x reference)
//
#include <hip/hip_runtime.h>

// Fused RNN: encoders + 576-step LSTM + projection + softmax.
// 256 blocks x 1024 threads (16 waves = 4/SIMD), 4 batches/block, 1 block/CU.
// Latency-bound: kernel time = 576 x (barrier-to-barrier critical path).
//
// Round-17: R16 (396us, best) + chain-exposure/micro-op diet. No structure change.
//  - Accounting fix: VALUBusy includes MFMA issue on CDNA -> pure VALU ~270cy;
//    step 1514cy = matrix 451 + VALU 270 + LDS ~400 (shared per-CU) +
//    ~400 exposure/barrier. This round attacks the exposure term:
//    (a) MFMA chain split 4->2 per tile (accA=kc01, accB=kc23, add at ACT):
//        halves dependent-MFMA depth on the exposed tail; +8 add/4 sel cost.
//    (b) zero-register acc init: first MFMA takes persistent zeroed f32x4 as
//        C operand -> deletes 8 v_mov per wave per step.
//    (c) staging parity is the compile-time PP literal (dead-branch removed).
//  - Everything else identical to R16: 16 thin waves (w0..11 = 2 tiles,
//    w12 = 1, w15 = proj+SMAX, w14 = staging, w13 idle), pre-scaled gate
//    columns (-log2e / -2log2e / proj +log2e -> bare v_exp_f32), x2-unrolled
//    loop with literal phase, LDS-only barrier (no vmcnt drain),
//    proj-as-MFMA-tile, D-frag==activation layout, reg-held encoder weights,
//    distance-2 prefetch, padded Y (stride 144).
//  - Falsified structure space: 1 wave/SIMD (R11 +110%), K-split barriers
//    (R14 +54%), s_sleep stagger (R15 +11%), merged-rcp ACT (R12 -9%).

#define NTHR 1024
#define L2E 1.4426950408889634f

typedef _Float16 half8 __attribute__((ext_vector_type(8)));
typedef float    f32x4 __attribute__((ext_vector_type(4)));

struct __align__(16) SM {
  _Float16 Y[2][4][144];   // [phase][batch][k]: h(0..99), x(100..108), 1(109), 0(110..143)
};

__device__ __forceinline__ float fexp2(float x) {
#if defined(__has_builtin)
#if __has_builtin(__builtin_amdgcn_exp2f)
  return __builtin_amdgcn_exp2f(x);
#else
  return __builtin_exp2f(x);
#endif
#else
  return __builtin_exp2f(x);
#endif
}

// sigmoid(z) given z' = -z*log2e ; tanh(z) given z' = -2z*log2e
__device__ __forceinline__ float sig2(float zp) {
  return __builtin_amdgcn_rcpf(1.f + fexp2(zp));
}
__device__ __forceinline__ float tanh2(float zp) {
  return fmaf(2.f, __builtin_amdgcn_rcpf(1.f + fexp2(zp)), -1.f);
}

// W~ row k of column n: k<100 -> W_h, 100..108 -> W_x, 109 -> b_lstm, else 0.
__device__ __forceinline__ float wld(int k, int n,
                                     const float* __restrict__ Wh,
                                     const float* __restrict__ Wx,
                                     const float* __restrict__ bl) {
  if (k < 100)  return Wh[k * 400 + n];
  if (k < 109)  return Wx[(k - 100) * 400 + n];
  if (k == 109) return bl[n];
  return 0.f;
}

// Projection column m (out-dim): rows = h, bias at 109, zeros elsewhere.
__device__ __forceinline__ float wproj(int k, int m,
                                       const float* __restrict__ Wo,
                                       const float* __restrict__ bo) {
  if (m >= 9)   return 0.f;
  if (k < 100)  return Wo[k * 9 + m];
  if (k == 109) return bo[m];
  return 0.f;
}

// LDS-only barrier: do NOT drain vmcnt (global prefetch/stores stay in flight).
__device__ __forceinline__ void sync_lds() {
  asm volatile("s_waitcnt lgkmcnt(0)" ::: "memory");
  __builtin_amdgcn_s_barrier();
  asm volatile("" ::: "memory");
}

__global__ __launch_bounds__(NTHR, 4)
void lstm_fused(const float* __restrict__ g_input,
                const float* __restrict__ g_task,
                const float* __restrict__ g_Win,
                const float* __restrict__ g_bin,
                const float* __restrict__ g_Wtask,
                const float* __restrict__ g_btask,
                const float* __restrict__ g_Wx,
                const float* __restrict__ g_Wh,
                const float* __restrict__ g_bl,
                const float* __restrict__ g_Wout,
                const float* __restrict__ g_bout,
                float* __restrict__ g_out)
{
  __shared__ SM L;
  const int tid  = threadIdx.x;
  const int bg0  = blockIdx.x * 4;
  const int wv   = tid >> 6;        // wave id 0..15 (4 per SIMD)
  const int lane = tid & 63;
  const int q    = lane >> 4;       // MFMA k-quad
  const int nl   = lane & 15;       // A row m / B-D col n
  const int hi   = lane >> 4;       // D row group (unit-in-tile)
  const int xr_  = nl >> 2;         // replica -> tile select
  const int ab   = nl & 3;          // batch

  // ---- cooperative LDS fill: Y = 0 except k==109 -> 1.0 (bias slot) ----
  for (int i = tid; i < 2 * 4 * 144; i += NTHR)
    ((_Float16*)L.Y)[i] = ((i % 144) == 109) ? (_Float16)1.f : (_Float16)0.f;

  // ---- tile ownership: w0..11 = 2 tiles, w12 = 1, w15 = proj, w13/w14 = 0 ----
  const int NR    = (wv < 12) ? 2 : (wv == 12) ? 1 : 0;    // recurrent tiles
  const int NTF   = (wv == 15) ? 1 : NR;                   // fragment slots
  const int tbase = (wv < 12) ? wv * 2 : 24;

  // ---- A-fragments: weights, reg-stationary, PRE-SCALED for exp2 ----
  // m = nl = 4*Uin + gate; column n = gate*100 + (tbase+ti)*4 + Uin.
  // scale: i,f,o gates -log2e; g gate -2log2e; proj +log2e.
  half8 Af[2][4];   // [ti][kc]; lane holds A[m=nl][k=kc*32+q*8+j]
  {
    const int gate = ab;
    const int Uin  = xr_;
    const float scl = (gate == 2) ? (-2.f * L2E) : (-L2E);
#pragma unroll
    for (int ti = 0; ti < 2; ++ti) {
      if (ti < NTF) {
        const bool proj = (wv == 15);
        const int n = gate * 100 + (tbase + ti) * 4 + Uin;
#pragma unroll
        for (int kc = 0; kc < 4; ++kc) {
#pragma unroll
          for (int j = 0; j < 8; ++j) {
            const int k = kc * 32 + q * 8 + j;
            Af[ti][kc][j] = (_Float16)(proj ? wproj(k, nl, g_Wout, g_bout) * L2E
                                            : wld(k, n, g_Wh, g_Wx, g_bl) * scl);
          }
        }
      }
    }
  }

  // persistent zeroed accumulator seed (C operand of first MFMA in each chain)
  const f32x4 Z4 = {0.f, 0.f, 0.f, 0.f};

  // ---- activation ownership: lane (x,hi,b) -> unit (tbase + (x&1))*4 + hi ----
  const int aU = (tbase + ((NR == 2) ? (xr_ & 1) : 0)) * 4 + hi;
  float c_state = 0.f;

  // ---- wave-14 staging role: lanes 28..63 -> 36 items (b = sl/9, f = sl%9) ----
  const int sl  = lane - 28;
  const int stb = (sl >= 0) ? sl / 9 : 0;
  const int stf = (sl >= 0) ? sl % 9 : 0;
  float we_in[9], we_task[9], be_in = 0.f, be_task = 0.f;
  if (wv == 14) {
#pragma unroll
    for (int ff = 0; ff < 9; ++ff) {
      we_in[ff]   = g_Win[ff * 9 + stf];
      we_task[ff] = g_Wtask[ff * 9 + stf];
    }
    be_in = g_bin[stf]; be_task = g_btask[stf];
  }
  float xrA[9], xrB[9];   // prefetch buffers: xrB = odd times, xrA = even times

  auto LOADX = [&](float* xr, int tt) {
    const float* src = (tt < 512)
      ? g_input + ((long)(bg0 + stb) * 512 + tt) * 9
      : g_task  + ((long)(bg0 + stb) * 64 + (tt - 512)) * 9;
#pragma unroll
    for (int ff = 0; ff < 9; ++ff) xr[ff] = src[ff];
  };
  auto ENC9 = [&](const float* xr, const float (&w)[9], float b) -> float {
    float a0 = b, a1 = 0.f, a2 = 0.f;
    a0 = fmaf(xr[0], w[0], a0); a1 = fmaf(xr[1], w[1], a1); a2 = fmaf(xr[2], w[2], a2);
    a0 = fmaf(xr[3], w[3], a0); a1 = fmaf(xr[4], w[4], a1); a2 = fmaf(xr[5], w[5], a2);
    a0 = fmaf(xr[6], w[6], a0); a1 = fmaf(xr[7], w[7], a1); a2 = fmaf(xr[8], w[8], a2);
    return (a0 + a1) + a2;
  };
  auto ENCSTEP = [&](const float* xr, int tt) {
    float a;
    if (tt < 512) a = ENC9(xr, we_in, be_in);
    else          a = ENC9(xr, we_task, be_task);
    L.Y[tt & 1][stb][100 + stf] = (_Float16)fmaxf(a, 0.f);
  };
  // activation: zv pre-scaled -> exp2 direct; R10 op structure (no merged rcp)
  auto ACT = [&](int p, const float* zv) {
    const float gi = sig2(zv[0]);
    const float gf = sig2(zv[1]);
    const float gg = tanh2(zv[2]);
    const float go = sig2(zv[3]);
    c_state = fmaf(gf, c_state, gi * gg);
    const float th = tanh2(c_state * (-2.f * L2E));
    L.Y[p ^ 1][ab][aU] = (_Float16)(go * th);
  };
  // softmax over the projection D-fragment (w15 xr_==0 lanes: logits[4hi+r][ab],
  // pre-scaled by log2e -> exp2 direct; softmax value unchanged)
  auto SMAX = [&](f32x4 v, int tout) {
    float e0 = fexp2(v[0]), e1 = fexp2(v[1]), e2 = fexp2(v[2]), e3 = fexp2(v[3]);
    if (hi == 2) { e1 = 0.f; e2 = 0.f; e3 = 0.f; }
    if (hi == 3) { e0 = 0.f; e1 = 0.f; e2 = 0.f; e3 = 0.f; }
    const float pl = (e0 + e1) + (e2 + e3);
    const float s1 = pl + __uint_as_float(__builtin_amdgcn_ds_swizzle(__float_as_uint(pl), 0x401F));
    const float ss = s1 + __shfl_xor(s1, 32, 64);
    const float rs = __builtin_amdgcn_rcpf(ss);
    if (hi < 3) {
      float* dst = g_out + ((long)(bg0 + ab) * 576 + tout) * 9 + 4 * hi;
      dst[0] = e0 * rs;
      if (hi < 2) { dst[1] = e1 * rs; dst[2] = e2 * rs; dst[3] = e3 * rs; }
    }
  };

  sync_lds();   // Y zero-fill visible

  // ---- prologue (wave 14): stage encoded s_0 into Y[0]; prefetch x(1),x(2) ----
  if (wv == 14 && sl >= 0) {
    float x0[9];
    LOADX(x0, 0);
    L.Y[0][stb][100 + stf] = (_Float16)fmaxf(ENC9(x0, we_in, be_in), 0.f);
    LOADX(xrB, 1);
    LOADX(xrA, 2);
  }
  sync_lds();

  // ---- main recurrence: ONE LDS-only barrier per step; x2 unrolled so the
  // phase PP is a compile-time literal (static LDS offsets, no selects).
  // MFMA chains split kc01/kc23 (accA/accB) -> half the dependent depth. ----
#define STEP_BODY(PP, TT)                                                      \
  {                                                                            \
    half8 Bv[4];                                                               \
    f32x4 accA[2], accB[2];                                                    \
    if (NTF > 0) {                                                             \
      _Pragma("unroll")                                                        \
      for (int kc = 0; kc < 4; ++kc)                                           \
        Bv[kc] = *(const half8*)&L.Y[PP][ab][kc * 32 + q * 8];                 \
      _Pragma("unroll")                                                        \
      for (int ti = 0; ti < 2; ++ti) {                                         \
        if (ti < NTF) {                                                        \
          accA[ti] = __builtin_amdgcn_mfma_f32_16x16x32_f16(Af[ti][0], Bv[0], Z4, 0, 0, 0); \
          accB[ti] = __builtin_amdgcn_mfma_f32_16x16x32_f16(Af[ti][2], Bv[2], Z4, 0, 0, 0); \
          accA[ti] = __builtin_amdgcn_mfma_f32_16x16x32_f16(Af[ti][1], Bv[1], accA[ti], 0, 0, 0); \
          accB[ti] = __builtin_amdgcn_mfma_f32_16x16x32_f16(Af[ti][3], Bv[3], accB[ti], 0, 0, 0); \
        }                                                                      \
      }                                                                        \
    }                                                                          \
    if (NR > 0) {                                                              \
      if (xr_ < NR) {                                                          \
        float zv[4];                                                           \
        _Pragma("unroll")                                                      \
        for (int g = 0; g < 4; ++g) {                                          \
          const float za = (NR == 2 && (xr_ & 1)) ? accA[1][g] : accA[0][g];   \
          const float zb = (NR == 2 && (xr_ & 1)) ? accB[1][g] : accB[0][g];   \
          zv[g] = za + zb;                                                     \
        }                                                                      \
        ACT(PP, zv);                                                           \
      }                                                                        \
    } else if (wv == 15) {                                                     \
      if (xr_ == 0 && (TT) > 0) {                                              \
        f32x4 pacc;                                                            \
        _Pragma("unroll")                                                      \
        for (int g = 0; g < 4; ++g) pacc[g] = accA[0][g] + accB[0][g];         \
        SMAX(pacc, (TT) - 1);                                                  \
      }                                                                        \
    } else if (wv == 14) {                                                     \
      if (sl >= 0 && (TT) + 1 < 576) {                                         \
        if (PP) { ENCSTEP(xrA, (TT) + 1); if ((TT) + 3 < 576) LOADX(xrA, (TT) + 3); } \
        else    { ENCSTEP(xrB, (TT) + 1); if ((TT) + 3 < 576) LOADX(xrB, (TT) + 3); } \
      }                                                                        \
    }                                                                          \
    sync_lds();                                                                \
  }

  for (int t = 0; t < 576; t += 2) {
    STEP_BODY(0, t);
    STEP_BODY(1, t + 1);
  }
#undef STEP_BODY

  // ---- tail: projection + softmax for t=575 (h[575] in Y[0]) ----
  if (wv == 15) {
    half8 Bv[4];
#pragma unroll
    for (int kc = 0; kc < 4; ++kc)
      Bv[kc] = *(const half8*)&L.Y[0][ab][kc * 32 + q * 8];
    f32x4 a0 = Z4;
#pragma unroll
    for (int kc = 0; kc < 4; ++kc)
      a0 = __builtin_amdgcn_mfma_f32_16x16x32_f16(Af[0][kc], Bv[kc], a0, 0, 0, 0);
    if (xr_ == 0) SMAX(a0, 575);
  }
}

extern "C" void kernel_launch(void* const* d_in, const int* in_sizes, int n_in,
                              void* d_out, int out_size, void* d_ws, size_t ws_size,
                              hipStream_t stream) {
  const float* input  = (const float*)d_in[0];
  const float* task   = (const float*)d_in[1];
  const float* W_in   = (const float*)d_in[2];
  const float* b_in   = (const float*)d_in[3];
  const float* W_task = (const float*)d_in[4];
  const float* b_task = (const float*)d_in[5];
  const float* W_x    = (const float*)d_in[6];
  const float* W_h    = (const float*)d_in[7];
  const float* b_lstm = (const float*)d_in[8];
  const float* W_out  = (const float*)d_in[9];
  const float* b_out  = (const float*)d_in[10];
  float* out = (float*)d_out;

  lstm_fused<<<256, NTHR, 0, stream>>>(input, task, W_in, b_in, W_task, b_task,
                                       W_x, W_h, b_lstm, W_out, b_out, out);
}

// Round 12
// 393.857 us; speedup vs baseline: 1.0555x; 1.0555x over previous
//
#include <hip/hip_runtime.h>

// Fused RNN: encoders + 576-step LSTM + projection + softmax.
// 256 blocks x 1024 threads (16 waves = 4/SIMD), 4 batches/block, 1 block/CU.
// Latency-bound: kernel time = 576 x (barrier-to-barrier critical path).
//
// Round-18: REVERT to R16 (395.5us, session best). R17's chain split
// regressed 5%: the split's 8 adds + extra selects are serial-after-MFMA
// (VALUBusy 47.7->52.6) while the dependent-MFMA tail it targeted was not a
// real exposure term (back-to-back dependent MFMAs pay ~throughput cost).
//
// Final structure (journal):
//  - 16 thin waves: w0..11 = 2 rec tiles each (tiles 0..23), w12 = tile 24,
//    w15 = projection tile + softmax, w14 = encoder staging, w13 idle.
//  - Weights reg-stationary as MFMA A-fragments, gate-permuted columns so the
//    D-fragment IS the activation layout (no Z round-trip); proj rides the
//    same y-vector as a 26th tile; bias via y[109]=1 slot.
//  - Gate columns pre-scaled by -log2e / -2log2e (g) / +log2e (proj):
//    activations use bare v_exp_f32; sigmoid=rcp(1+exp2), tanh=fma(2,rcp,-1).
//  - x2-unrolled loop with compile-time phase -> static LDS offsets.
//  - LDS-only barrier (s_waitcnt lgkmcnt(0) + s_barrier): global prefetch
//    (distance-2) and output stores stay in flight across steps.
//  - Step budget ~1514cy: matrix 451 + VALU ~270 + LDS ~400 + barrier/
//    exposure ~400. Falsified: 1 wave/SIMD (+110%), K-split barriers (+54%),
//    sleep stagger (+11%), merged-rcp ACT (-9%), MFMA chain split (-5%).

#define NTHR 1024
#define L2E 1.4426950408889634f

typedef _Float16 half8 __attribute__((ext_vector_type(8)));
typedef float    f32x4 __attribute__((ext_vector_type(4)));

struct __align__(16) SM {
  _Float16 Y[2][4][144];   // [phase][batch][k]: h(0..99), x(100..108), 1(109), 0(110..143)
};

__device__ __forceinline__ float fexp2(float x) {
#if defined(__has_builtin)
#if __has_builtin(__builtin_amdgcn_exp2f)
  return __builtin_amdgcn_exp2f(x);
#else
  return __builtin_exp2f(x);
#endif
#else
  return __builtin_exp2f(x);
#endif
}

// sigmoid(z) given z' = -z*log2e ; tanh(z) given z' = -2z*log2e
__device__ __forceinline__ float sig2(float zp) {
  return __builtin_amdgcn_rcpf(1.f + fexp2(zp));
}
__device__ __forceinline__ float tanh2(float zp) {
  return fmaf(2.f, __builtin_amdgcn_rcpf(1.f + fexp2(zp)), -1.f);
}

// W~ row k of column n: k<100 -> W_h, 100..108 -> W_x, 109 -> b_lstm, else 0.
__device__ __forceinline__ float wld(int k, int n,
                                     const float* __restrict__ Wh,
                                     const float* __restrict__ Wx,
                                     const float* __restrict__ bl) {
  if (k < 100)  return Wh[k * 400 + n];
  if (k < 109)  return Wx[(k - 100) * 400 + n];
  if (k == 109) return bl[n];
  return 0.f;
}

// Projection column m (out-dim): rows = h, bias at 109, zeros elsewhere.
__device__ __forceinline__ float wproj(int k, int m,
                                       const float* __restrict__ Wo,
                                       const float* __restrict__ bo) {
  if (m >= 9)   return 0.f;
  if (k < 100)  return Wo[k * 9 + m];
  if (k == 109) return bo[m];
  return 0.f;
}

// LDS-only barrier: do NOT drain vmcnt (global prefetch/stores stay in flight).
__device__ __forceinline__ void sync_lds() {
  asm volatile("s_waitcnt lgkmcnt(0)" ::: "memory");
  __builtin_amdgcn_s_barrier();
  asm volatile("" ::: "memory");
}

__global__ __launch_bounds__(NTHR, 4)
void lstm_fused(const float* __restrict__ g_input,
                const float* __restrict__ g_task,
                const float* __restrict__ g_Win,
                const float* __restrict__ g_bin,
                const float* __restrict__ g_Wtask,
                const float* __restrict__ g_btask,
                const float* __restrict__ g_Wx,
                const float* __restrict__ g_Wh,
                const float* __restrict__ g_bl,
                const float* __restrict__ g_Wout,
                const float* __restrict__ g_bout,
                float* __restrict__ g_out)
{
  __shared__ SM L;
  const int tid  = threadIdx.x;
  const int bg0  = blockIdx.x * 4;
  const int wv   = tid >> 6;        // wave id 0..15 (4 per SIMD)
  const int lane = tid & 63;
  const int q    = lane >> 4;       // MFMA k-quad
  const int nl   = lane & 15;       // A row m / B-D col n
  const int hi   = lane >> 4;       // D row group (unit-in-tile)
  const int xr_  = nl >> 2;         // replica -> tile select
  const int ab   = nl & 3;          // batch

  // ---- cooperative LDS fill: Y = 0 except k==109 -> 1.0 (bias slot) ----
  for (int i = tid; i < 2 * 4 * 144; i += NTHR)
    ((_Float16*)L.Y)[i] = ((i % 144) == 109) ? (_Float16)1.f : (_Float16)0.f;

  // ---- tile ownership: w0..11 = 2 tiles, w12 = 1, w15 = proj, w13/w14 = 0 ----
  const int NR    = (wv < 12) ? 2 : (wv == 12) ? 1 : 0;    // recurrent tiles
  const int NTF   = (wv == 15) ? 1 : NR;                   // fragment slots
  const int tbase = (wv < 12) ? wv * 2 : 24;

  // ---- A-fragments: weights, reg-stationary, PRE-SCALED for exp2 ----
  // m = nl = 4*Uin + gate; column n = gate*100 + (tbase+ti)*4 + Uin.
  // scale: i,f,o gates -log2e; g gate -2log2e; proj +log2e.
  half8 Af[2][4];   // [ti][kc]; lane holds A[m=nl][k=kc*32+q*8+j]
  {
    const int gate = ab;
    const int Uin  = xr_;
    const float scl = (gate == 2) ? (-2.f * L2E) : (-L2E);
#pragma unroll
    for (int ti = 0; ti < 2; ++ti) {
      if (ti < NTF) {
        const bool proj = (wv == 15);
        const int n = gate * 100 + (tbase + ti) * 4 + Uin;
#pragma unroll
        for (int kc = 0; kc < 4; ++kc) {
#pragma unroll
          for (int j = 0; j < 8; ++j) {
            const int k = kc * 32 + q * 8 + j;
            Af[ti][kc][j] = (_Float16)(proj ? wproj(k, nl, g_Wout, g_bout) * L2E
                                            : wld(k, n, g_Wh, g_Wx, g_bl) * scl);
          }
        }
      }
    }
  }

  // ---- activation ownership: lane (x,hi,b) -> unit (tbase + (x&1))*4 + hi ----
  const int aU = (tbase + ((NR == 2) ? (xr_ & 1) : 0)) * 4 + hi;
  float c_state = 0.f;

  // ---- wave-14 staging role: lanes 28..63 -> 36 items (b = sl/9, f = sl%9) ----
  const int sl  = lane - 28;
  const int stb = (sl >= 0) ? sl / 9 : 0;
  const int stf = (sl >= 0) ? sl % 9 : 0;
  float we_in[9], we_task[9], be_in = 0.f, be_task = 0.f;
  if (wv == 14) {
#pragma unroll
    for (int ff = 0; ff < 9; ++ff) {
      we_in[ff]   = g_Win[ff * 9 + stf];
      we_task[ff] = g_Wtask[ff * 9 + stf];
    }
    be_in = g_bin[stf]; be_task = g_btask[stf];
  }
  float xrA[9], xrB[9];   // prefetch buffers: xrB = odd times, xrA = even times

  auto LOADX = [&](float* xr, int tt) {
    const float* src = (tt < 512)
      ? g_input + ((long)(bg0 + stb) * 512 + tt) * 9
      : g_task  + ((long)(bg0 + stb) * 64 + (tt - 512)) * 9;
#pragma unroll
    for (int ff = 0; ff < 9; ++ff) xr[ff] = src[ff];
  };
  auto ENC9 = [&](const float* xr, const float (&w)[9], float b) -> float {
    float a0 = b, a1 = 0.f, a2 = 0.f;
    a0 = fmaf(xr[0], w[0], a0); a1 = fmaf(xr[1], w[1], a1); a2 = fmaf(xr[2], w[2], a2);
    a0 = fmaf(xr[3], w[3], a0); a1 = fmaf(xr[4], w[4], a1); a2 = fmaf(xr[5], w[5], a2);
    a0 = fmaf(xr[6], w[6], a0); a1 = fmaf(xr[7], w[7], a1); a2 = fmaf(xr[8], w[8], a2);
    return (a0 + a1) + a2;
  };
  auto ENCSTEP = [&](const float* xr, int tt) {
    float a;
    if (tt < 512) a = ENC9(xr, we_in, be_in);
    else          a = ENC9(xr, we_task, be_task);
    L.Y[tt & 1][stb][100 + stf] = (_Float16)fmaxf(a, 0.f);
  };
  // activation: zv pre-scaled -> exp2 direct; R10 op structure (no merged rcp)
  auto ACT = [&](int p, const float* zv) {
    const float gi = sig2(zv[0]);
    const float gf = sig2(zv[1]);
    const float gg = tanh2(zv[2]);
    const float go = sig2(zv[3]);
    c_state = fmaf(gf, c_state, gi * gg);
    const float th = tanh2(c_state * (-2.f * L2E));
    L.Y[p ^ 1][ab][aU] = (_Float16)(go * th);
  };
  // softmax over the projection D-fragment (w15 xr_==0 lanes: logits[4hi+r][ab],
  // pre-scaled by log2e -> exp2 direct; softmax value unchanged)
  auto SMAX = [&](f32x4 v, int tout) {
    float e0 = fexp2(v[0]), e1 = fexp2(v[1]), e2 = fexp2(v[2]), e3 = fexp2(v[3]);
    if (hi == 2) { e1 = 0.f; e2 = 0.f; e3 = 0.f; }
    if (hi == 3) { e0 = 0.f; e1 = 0.f; e2 = 0.f; e3 = 0.f; }
    const float pl = (e0 + e1) + (e2 + e3);
    const float s1 = pl + __uint_as_float(__builtin_amdgcn_ds_swizzle(__float_as_uint(pl), 0x401F));
    const float ss = s1 + __shfl_xor(s1, 32, 64);
    const float rs = __builtin_amdgcn_rcpf(ss);
    if (hi < 3) {
      float* dst = g_out + ((long)(bg0 + ab) * 576 + tout) * 9 + 4 * hi;
      dst[0] = e0 * rs;
      if (hi < 2) { dst[1] = e1 * rs; dst[2] = e2 * rs; dst[3] = e3 * rs; }
    }
  };

  sync_lds();   // Y zero-fill visible

  // ---- prologue (wave 14): stage encoded s_0 into Y[0]; prefetch x(1),x(2) ----
  if (wv == 14 && sl >= 0) {
    float x0[9];
    LOADX(x0, 0);
    L.Y[0][stb][100 + stf] = (_Float16)fmaxf(ENC9(x0, we_in, be_in), 0.f);
    LOADX(xrB, 1);
    LOADX(xrA, 2);
  }
  sync_lds();

  // ---- main recurrence: ONE LDS-only barrier per step; x2 unrolled so the
  // phase PP is a compile-time literal (static LDS offsets, no selects) ----
#define STEP_BODY(PP, TT)                                                      \
  {                                                                            \
    half8 Bv[4];                                                               \
    f32x4 acc[2];                                                              \
    if (NTF > 0) {                                                             \
      _Pragma("unroll")                                                        \
      for (int kc = 0; kc < 4; ++kc)                                           \
        Bv[kc] = *(const half8*)&L.Y[PP][ab][kc * 32 + q * 8];                 \
      _Pragma("unroll")                                                        \
      for (int ti = 0; ti < 2; ++ti) {                                         \
        if (ti < NTF) {                                                        \
          acc[ti] = (f32x4)0.f;                                                \
          _Pragma("unroll")                                                    \
          for (int kc = 0; kc < 4; ++kc)                                       \
            acc[ti] = __builtin_amdgcn_mfma_f32_16x16x32_f16(Af[ti][kc], Bv[kc], acc[ti], 0, 0, 0); \
        }                                                                      \
      }                                                                        \
    }                                                                          \
    if (NR > 0) {                                                              \
      if (xr_ < NR) {                                                          \
        float zv[4];                                                           \
        _Pragma("unroll")                                                      \
        for (int g = 0; g < 4; ++g)                                            \
          zv[g] = (NR == 2 && (xr_ & 1)) ? acc[1][g] : acc[0][g];              \
        ACT(PP, zv);                                                           \
      }                                                                        \
    } else if (wv == 15) {                                                     \
      if (xr_ == 0 && (TT) > 0) SMAX(acc[0], (TT) - 1);                        \
    } else if (wv == 14) {                                                     \
      if (sl >= 0 && (TT) + 1 < 576) {                                         \
        if ((TT) & 1) { ENCSTEP(xrA, (TT) + 1); if ((TT) + 3 < 576) LOADX(xrA, (TT) + 3); } \
        else          { ENCSTEP(xrB, (TT) + 1); if ((TT) + 3 < 576) LOADX(xrB, (TT) + 3); } \
      }                                                                        \
    }                                                                          \
    sync_lds();                                                                \
  }

  for (int t = 0; t < 576; t += 2) {
    STEP_BODY(0, t);
    STEP_BODY(1, t + 1);
  }
#undef STEP_BODY

  // ---- tail: projection + softmax for t=575 (h[575] in Y[0]) ----
  if (wv == 15) {
    half8 Bv[4];
#pragma unroll
    for (int kc = 0; kc < 4; ++kc)
      Bv[kc] = *(const half8*)&L.Y[0][ab][kc * 32 + q * 8];
    f32x4 a0 = (f32x4)0.f;
#pragma unroll
    for (int kc = 0; kc < 4; ++kc)
      a0 = __builtin_amdgcn_mfma_f32_16x16x32_f16(Af[0][kc], Bv[kc], a0, 0, 0, 0);
    if (xr_ == 0) SMAX(a0, 575);
  }
}

extern "C" void kernel_launch(void* const* d_in, const int* in_sizes, int n_in,
                              void* d_out, int out_size, void* d_ws, size_t ws_size,
                              hipStream_t stream) {
  const float* input  = (const float*)d_in[0];
  const float* task   = (const float*)d_in[1];
  const float* W_in   = (const float*)d_in[2];
  const float* b_in   = (const float*)d_in[3];
  const float* W_task = (const float*)d_in[4];
  const float* b_task = (const float*)d_in[5];
  const float* W_x    = (const float*)d_in[6];
  const float* W_h    = (const float*)d_in[7];
  const float* b_lstm = (const float*)d_in[8];
  const float* W_out  = (const float*)d_in[9];
  const float* b_out  = (const float*)d_in[10];
  float* out = (float*)d_out;

  lstm_fused<<<256, NTHR, 0, stream>>>(input, task, W_in, b_in, W_task, b_task,
                                       W_x, W_h, b_lstm, W_out, b_out, out);
}